// Round 1
// baseline (117.326 us; speedup 1.0000x reference)
//
#include <hip/hip_runtime.h>
#include <math.h>

#define N      512
#define RNUM   4
#define BNUM   2
#define NSLICE (RNUM * BNUM)
#define TILE   128               // (a,b) tile 128x128, 256 threads x (8x8)
#define CT     64                // c-chunk per block (f16 tiles) -- R9: 32->64
#define LSTR   136               // f16 row stride (272 B) - bank-verified
#define CSPLIT 8                 // c-split -> 1024 main blocks (4/CU, 1 round)
#define NCOLB  16                // colsum-role blocks (8 slices x 2 halves)
#define SCALE  0.0625f           // (1/2 relu-split) * (1/8 weight/(R*B))

typedef _Float16 half2_t __attribute__((ext_vector_type(2)));

__device__ __forceinline__ unsigned int h2u(half2_t h) {
  return __builtin_bit_cast(unsigned int, h);
}
__device__ __forceinline__ half2_t u2h(unsigned int u) {
  return __builtin_bit_cast(half2_t, u);
}

#if __has_builtin(__builtin_amdgcn_fdot2)
__device__ __forceinline__ float fdot2_(half2_t a, half2_t b, float c) {
  return __builtin_amdgcn_fdot2(a, b, c, false);
}
#else
__device__ __forceinline__ float fdot2_(half2_t a, half2_t b, float c) {
  return c + (float)a.x * (float)b.x + (float)a.y * (float)b.y;
}
#endif

__device__ __forceinline__ float sigmoidf_(float x) {
  return 1.0f / (1.0f + __expf(-x));
}

__global__ void zero_out_kernel(float* out) { out[0] = 0.0f; }

// One thread per (b,i,j): reads float4 over r, writes 4 f16 slice planes
// P[s][i][j] (row-major, mask+sigmoid folded). Coalesced 2B stores.
// Block 0 thread 0 zeroes the output accumulator.
__global__ __launch_bounds__(256) void prep_f16_kernel(const float* __restrict__ logits,
                                                       const int* __restrict__ masks,
                                                       _Float16* __restrict__ P,
                                                       float* __restrict__ out) {
  if (blockIdx.x == 0 && threadIdx.x == 0) out[0] = 0.0f;
  int t = blockIdx.x * 256 + threadIdx.x;      // 0 .. B*N*N-1
  int b = t >> 18;                              // / (N*N)
  int rem = t & (N * N - 1);
  int i = rem >> 9;
  int j = rem & (N - 1);
  float4 lg = *(const float4*)(logits + (size_t)t * 4);
  float mm = ((masks[b * N + i] > 0) && (masks[b * N + j] > 0)) ? 1.0f : 0.0f;
  size_t base = (size_t)b * RNUM * N * N + rem;
  P[base + 0 * (size_t)N * N] = (_Float16)(mm * sigmoidf_(lg.x));
  P[base + 1 * (size_t)N * N] = (_Float16)(mm * sigmoidf_(lg.y));
  P[base + 2 * (size_t)N * N] = (_Float16)(mm * sigmoidf_(lg.z));
  P[base + 3 * (size_t)N * N] = (_Float16)(mm * sigmoidf_(lg.w));
}

// Work kernel (f16 path), two roles by blockIdx.x:
//  bid <  NCOLB : colsum role — Sum_c csum_c*(N-csum_c)  (factorized Sum(x);
//                 lanes read consecutive c at fixed a -> coalesced)
//  bid >= NCOLB : main role — Sum |rab - a_c*b_c| via packed f16:
//    per 2 elements: v_pk_fma_f16 + v_and (packed abs) + v_dot2_f32_f16
//    = 1.5 VALU inst/elem, f32 accumulation via dot2.
// LDS tiles [c][x] f16, stride LSTR=136 (272 B): conflict-free (verified).
//
// R9 changes (theory: VGPR_Count=28 cannot hold rab2[8][4]=32 regs -> compiler
// was bouncing the operand tile through AGPRs/rematerialized loads, ~2x VALU
// issue bloat; plus 31% idle from per-block prologue at CSPLIT=16):
//  * __launch_bounds__(256,4): 128-VGPR budget, rab2 register-resident.
//    4 blocks/CU (LDS 34.8KB x4 = 139KB <= 160KB) = 16 waves/CU, same as the
//    measured 47.8% occupancy of the old config — no occupancy loss.
//  * CT=64, CSPLIT=8: 1024 main blocks = exactly one 4/CU round; half the
//    prologues, half the rab tile re-reads.
//  * Row-pair staging: each thread transposes TWO rows x 32 c, packing
//    {r0[c],r1[c]} u32 -> 32 ds_write_b32 (banks: 64 consecutive dwords per
//    wave = 2-way, free) instead of 64 ds_write_b16.
__global__ __launch_bounds__(256, 4) void work_f16_kernel(const _Float16* __restrict__ P,
                                                          float* __restrict__ out) {
  __shared__ _Float16 tA[CT][LSTR];
  __shared__ _Float16 tB[CT][LSTR];
  __shared__ float wsum[4];

  const int tid = threadIdx.x;
  const int bid = blockIdx.x;

  if (bid < NCOLB) {
    // ---- colsum role ----
    const int s    = bid >> 1;
    const int half = bid & 1;
    const int c    = half * 256 + tid;
    const _Float16* col = P + (size_t)s * N * N + c;
    float sum = 0.0f;
#pragma unroll 16
    for (int a = 0; a < N; ++a) sum += (float)col[(size_t)a * N];
    float v = sum * ((float)N - sum);
    for (int off = 32; off > 0; off >>= 1) v += __shfl_down(v, off, 64);
    const int wid = tid >> 6;
    if ((tid & 63) == 0) wsum[wid] = v;
    __syncthreads();
    if (tid == 0)
      atomicAdd(out, (wsum[0] + wsum[1] + wsum[2] + wsum[3]) * SCALE);
    return;
  }

  // ---- main role ----
  const int m  = bid - NCOLB;
  const int bt = m & 3;
  const int at = (m >> 2) & 3;
  const int s  = (m >> 4) & 7;
  const int cz = m >> 7;                    // 0..CSPLIT-1
  const int a0 = at * TILE;
  const int b0 = bt * TILE;
  const int c0 = cz * CT;                   // exactly one CT-chunk per block

  const int ta = tid & 15;    // a cols (tile-local): ta*4+0..3 and 64+ta*4+0..3
  const int tb = tid >> 4;    // b cols (tile-local): tb*4+0..3 and 64+tb*4+0..3

  const _Float16* Ph = P + (size_t)s * N * N;

  // staging: thread handles a ROW-PAIR (2 rows) x 32 c's, writes packed u32
  // {row0[c], row1[c]} into LDS column pair (2p, 2p+1).
  // mapping: u = tid&127 -> pair-unit (u<64: A rows, else B rows);
  //          h = tid>>7  -> c-half [32h, 32h+32).
  {
    const int u   = tid & 127;
    const int h   = tid >> 7;
    const int isB = u >> 6;
    const int p   = u & 63;                 // pair index within tile
    const int r0  = (isB ? b0 : a0) + 2 * p;
    const int cc0 = c0 + h * 32;
    const _Float16* s0row = Ph + (size_t)r0 * N + cc0;
    const _Float16* s1row = s0row + N;
    _Float16* dst = isB ? &tB[h * 32][2 * p] : &tA[h * 32][2 * p];
    uint4 q0 = ((const uint4*)s0row)[0];
    uint4 q1 = ((const uint4*)s0row)[1];
    uint4 q2 = ((const uint4*)s0row)[2];
    uint4 q3 = ((const uint4*)s0row)[3];
    uint4 p0 = ((const uint4*)s1row)[0];
    uint4 p1 = ((const uint4*)s1row)[1];
    uint4 p2 = ((const uint4*)s1row)[2];
    uint4 p3 = ((const uint4*)s1row)[3];
    unsigned int w0[16] = {q0.x, q0.y, q0.z, q0.w, q1.x, q1.y, q1.z, q1.w,
                           q2.x, q2.y, q2.z, q2.w, q3.x, q3.y, q3.z, q3.w};
    unsigned int w1[16] = {p0.x, p0.y, p0.z, p0.w, p1.x, p1.y, p1.z, p1.w,
                           p2.x, p2.y, p2.z, p2.w, p3.x, p3.y, p3.z, p3.w};
#pragma unroll
    for (int k = 0; k < 16; ++k) {
      unsigned int lo = (w1[k] << 16) | (w0[k] & 0xFFFFu);       // c = 2k
      unsigned int hi = (w1[k] & 0xFFFF0000u) | (w0[k] >> 16);   // c = 2k+1
      *(unsigned int*)(dst + (size_t)(2 * k) * LSTR)     = lo;
      *(unsigned int*)(dst + (size_t)(2 * k + 1) * LSTR) = hi;
    }
  }

  // rab as f16 pairs over y: rab2[x][yp] = {rab[x][2yp], rab[x][2yp+1]}
  // (loaded after staging-store issue so global latencies overlap; must stay
  //  VGPR-resident through the whole c-loop — hence the (256,4) bound)
  half2_t rab2[8][4];
#pragma unroll
  for (int x = 0; x < 8; ++x) {
    int ga = a0 + ((x >> 2) << 6) + ta * 4 + (x & 3);
    uint2 u0 = *(const uint2*)(Ph + (size_t)ga * N + b0 + tb * 4);
    uint2 u1 = *(const uint2*)(Ph + (size_t)ga * N + b0 + 64 + tb * 4);
    rab2[x][0] = u2h(u0.x); rab2[x][1] = u2h(u0.y);
    rab2[x][2] = u2h(u1.x); rab2[x][3] = u2h(u1.y);
  }

  float acc[8];
#pragma unroll
  for (int x = 0; x < 8; ++x) acc[x] = 0.0f;

  const half2_t kOne = {(_Float16)1.0f, (_Float16)1.0f};

  __syncthreads();

#pragma unroll 4
  for (int c = 0; c < CT; ++c) {
    uint2 ua0 = *(const uint2*)&tA[c][ta * 4];
    uint2 ua1 = *(const uint2*)&tA[c][64 + ta * 4];
    uint2 ub0 = *(const uint2*)&tB[c][tb * 4];
    uint2 ub1 = *(const uint2*)&tB[c][64 + tb * 4];
    half2_t av[4] = {u2h(ua0.x), u2h(ua0.y), u2h(ua1.x), u2h(ua1.y)};
    half2_t bv[4] = {u2h(ub0.x), u2h(ub0.y), u2h(ub1.x), u2h(ub1.y)};
#pragma unroll
    for (int x = 0; x < 8; ++x) {
      _Float16 as = (x & 1) ? av[x >> 1].y : av[x >> 1].x;
      half2_t asp = {as, as};
      float a_ = acc[x];
#pragma unroll
      for (int yp = 0; yp < 4; ++yp) {
        half2_t t2 = rab2[x][yp] - asp * bv[yp];     // v_pk_fma_f16 (neg)
        half2_t p2 = u2h(h2u(t2) & 0x7FFF7FFFu);     // packed |t|
        a_ = fdot2_(p2, kOne, a_);                   // f32 accumulate
      }
      acc[x] = a_;
    }
  }

  float tsum = 0.0f;
#pragma unroll
  for (int x = 0; x < 8; ++x) tsum += acc[x];

  for (int off = 32; off > 0; off >>= 1) tsum += __shfl_down(tsum, off, 64);

  const int wid = tid >> 6;
  if ((tid & 63) == 0) wsum[wid] = tsum;
  __syncthreads();
  if (tid == 0)
    atomicAdd(out, (wsum[0] + wsum[1] + wsum[2] + wsum[3]) * SCALE);
}

// ---------------- f32 fallback (no workspace): R4 structure ----------------
#define FCT    64
#define FSTR   132
#define FCSPL  4

__global__ __launch_bounds__(256, 2) void work_f32_fallback(const float* __restrict__ logits,
                                                            const int* __restrict__ masks,
                                                            float* __restrict__ out) {
  __shared__ __align__(16) float tA[FCT][FSTR];
  __shared__ __align__(16) float tB[FCT][FSTR];
  __shared__ float wsum[4];

  const int tid = threadIdx.x;
  const int bid = blockIdx.x;

  if (bid < NCOLB) {
    const int s    = bid >> 1;
    const int half = bid & 1;
    const int c    = half * 256 + tid;
    const int bb   = s >> 2;
    const int r    = s & 3;
    const int* mrow = masks + bb * N;
    float mc = (mrow[c] > 0) ? 1.0f : 0.0f;
    float sum = 0.0f;
#pragma unroll 4
    for (int a = 0; a < N; ++a) {
      float ma = (mrow[a] > 0) ? 1.0f : 0.0f;
      size_t idx = ((size_t)(bb * N + a) * N + c) * RNUM + r;
      sum += sigmoidf_(logits[idx]) * ma * mc;
    }
    float v = sum * ((float)N - sum);
    for (int off = 32; off > 0; off >>= 1) v += __shfl_down(v, off, 64);
    const int wid = tid >> 6;
    if ((tid & 63) == 0) wsum[wid] = v;
    __syncthreads();
    if (tid == 0)
      atomicAdd(out, (wsum[0] + wsum[1] + wsum[2] + wsum[3]) * SCALE);
    return;
  }

  const int m  = bid - NCOLB;
  const int bt = m & 3;
  const int at = (m >> 2) & 3;
  const int s  = (m >> 4) & 7;
  const int cz = m >> 7;
  const int a0 = at * TILE;
  const int b0 = bt * TILE;
  const int bb = s >> 2;
  const int r  = s & 3;
  const int cbeg = cz * (N / FCSPL);
  const int cend = cbeg + (N / FCSPL);

  const int ta = tid & 15;
  const int tb = tid >> 4;
  const int* mrow = masks + bb * N;

  float rab[8][8];
#pragma unroll
  for (int x = 0; x < 8; ++x) {
    int ra = a0 + ((x >> 2) << 6) + ta * 4 + (x & 3);
    float ma = (mrow[ra] > 0) ? 1.0f : 0.0f;
#pragma unroll
    for (int y = 0; y < 8; ++y) {
      int cb = b0 + ((y >> 2) << 6) + tb * 4 + (y & 3);
      float mb = (mrow[cb] > 0) ? 1.0f : 0.0f;
      size_t idx = ((size_t)(bb * N + ra) * N + cb) * RNUM + r;
      rab[x][y] = sigmoidf_(logits[idx]) * ma * mb;
    }
  }

  float acc[8][2];
#pragma unroll
  for (int x = 0; x < 8; ++x) { acc[x][0] = 0.0f; acc[x][1] = 0.0f; }

  for (int c0 = cbeg; c0 < cend; c0 += FCT) {
    __syncthreads();
#pragma unroll
    for (int it = 0; it < 32; ++it) {
      int e = it * 256 + tid;
      int c = e & 63;
      int i = e >> 6;
      int pc = ((((i >> 2) ^ ((c >> 2) & 31)) & 31) << 2) | (i & 3);
      float mc = (mrow[c0 + c] > 0) ? 1.0f : 0.0f;
      {
        float mi = (mrow[a0 + i] > 0) ? 1.0f : 0.0f;
        size_t idx = ((size_t)(bb * N + a0 + i) * N + (c0 + c)) * RNUM + r;
        tA[c][pc] = sigmoidf_(logits[idx]) * mi * mc;
      }
      {
        float mi = (mrow[b0 + i] > 0) ? 1.0f : 0.0f;
        size_t idx = ((size_t)(bb * N + b0 + i) * N + (c0 + c)) * RNUM + r;
        tB[c][pc] = sigmoidf_(logits[idx]) * mi * mc;
      }
    }
    __syncthreads();

#pragma unroll 2
    for (int cg = 0; cg < FCT / 4; ++cg) {
      const float* pa = &tA[cg * 4][((ta ^ cg) & 31) << 2];
      const float* pb = &tB[cg * 4][((tb ^ cg) & 31) << 2];
#pragma unroll
      for (int dc = 0; dc < 4; ++dc) {
        float4 a0v = *(const float4*)(pa + dc * FSTR);
        float4 a1v = *(const float4*)(pa + dc * FSTR + 64);
        float4 b0v = *(const float4*)(pb + dc * FSTR);
        float4 b1v = *(const float4*)(pb + dc * FSTR + 64);
        float avv[8] = {a0v.x, a0v.y, a0v.z, a0v.w, a1v.x, a1v.y, a1v.z, a1v.w};
        float bvv[8] = {b0v.x, b0v.y, b0v.z, b0v.w, b1v.x, b1v.y, b1v.z, b1v.w};
#pragma unroll
        for (int x = 0; x < 8; ++x) {
#pragma unroll
          for (int y = 0; y < 4; ++y)
            acc[x][0] += fabsf(fmaf(-avv[x], bvv[y], rab[x][y]));
#pragma unroll
          for (int y = 4; y < 8; ++y)
            acc[x][1] += fabsf(fmaf(-avv[x], bvv[y], rab[x][y]));
        }
      }
    }
  }

  float tsum = 0.0f;
#pragma unroll
  for (int x = 0; x < 8; ++x) tsum += acc[x][0] + acc[x][1];
  for (int off = 32; off > 0; off >>= 1) tsum += __shfl_down(tsum, off, 64);
  const int wid = tid >> 6;
  if ((tid & 63) == 0) wsum[wid] = tsum;
  __syncthreads();
  if (tid == 0)
    atomicAdd(out, (wsum[0] + wsum[1] + wsum[2] + wsum[3]) * SCALE);
}

extern "C" void kernel_launch(void* const* d_in, const int* in_sizes, int n_in,
                              void* d_out, int out_size, void* d_ws, size_t ws_size,
                              hipStream_t stream) {
  const float* logits = (const float*)d_in[0];
  const int*   masks  = (const int*)d_in[1];
  float*       out    = (float*)d_out;

  const size_t P_BYTES = (size_t)NSLICE * N * N * sizeof(_Float16);  // 4 MB

  if (ws_size >= P_BYTES) {
    _Float16* P = (_Float16*)d_ws;
    prep_f16_kernel<<<(BNUM * N * N) / 256, 256, 0, stream>>>(logits, masks, P, out);
    const int nblocks = NCOLB + 4 * 4 * NSLICE * CSPLIT;  // 16 + 1024
    work_f16_kernel<<<nblocks, 256, 0, stream>>>(P, out);
  } else {
    zero_out_kernel<<<1, 1, 0, stream>>>(out);
    const int nblocks = NCOLB + 4 * 4 * NSLICE * FCSPL;   // 16 + 512
    work_f32_fallback<<<nblocks, 256, 0, stream>>>(logits, masks, out);
  }
}

// Round 2
// 114.325 us; speedup vs baseline: 1.0262x; 1.0262x over previous
//
#include <hip/hip_runtime.h>
#include <math.h>

#define N      512
#define RNUM   4
#define BNUM   2
#define NSLICE (RNUM * BNUM)
#define TILE   128               // (a,b) tile 128x128, 256 threads x (8x8)
#define CT     32                // c-chunk per LDS stage (f16 tiles) -- R10: back to 32
#define LSTR   136               // f16 row stride (272 B = 17*16B) - bank-verified, 16B-aligned rows
#define CSPLIT 16                // c-split -> 2048 main blocks (~8/CU)
#define NCOLB  16                // colsum-role blocks (8 slices x 2 halves)
#define SCALE  0.0625f           // (1/2 relu-split) * (1/8 weight/(R*B))

typedef _Float16 half2_t __attribute__((ext_vector_type(2)));

__device__ __forceinline__ unsigned int h2u(half2_t h) {
  return __builtin_bit_cast(unsigned int, h);
}
__device__ __forceinline__ half2_t u2h(unsigned int u) {
  return __builtin_bit_cast(half2_t, u);
}

#if __has_builtin(__builtin_amdgcn_fdot2)
__device__ __forceinline__ float fdot2_(half2_t a, half2_t b, float c) {
  return __builtin_amdgcn_fdot2(a, b, c, false);
}
#else
__device__ __forceinline__ float fdot2_(half2_t a, half2_t b, float c) {
  return c + (float)a.x * (float)b.x + (float)a.y * (float)b.y;
}
#endif

__device__ __forceinline__ float sigmoidf_(float x) {
  return 1.0f / (1.0f + __expf(-x));
}

__global__ void zero_out_kernel(float* out) { out[0] = 0.0f; }

// One thread per (b,i,j): reads float4 over r, writes 4 f16 slice planes
// P[s][i][j] (row-major, mask+sigmoid folded). Coalesced 2B stores.
// Block 0 thread 0 zeroes the output accumulator.
__global__ __launch_bounds__(256) void prep_f16_kernel(const float* __restrict__ logits,
                                                       const int* __restrict__ masks,
                                                       _Float16* __restrict__ P,
                                                       float* __restrict__ out) {
  if (blockIdx.x == 0 && threadIdx.x == 0) out[0] = 0.0f;
  int t = blockIdx.x * 256 + threadIdx.x;      // 0 .. B*N*N-1
  int b = t >> 18;                              // / (N*N)
  int rem = t & (N * N - 1);
  int i = rem >> 9;
  int j = rem & (N - 1);
  float4 lg = *(const float4*)(logits + (size_t)t * 4);
  float mm = ((masks[b * N + i] > 0) && (masks[b * N + j] > 0)) ? 1.0f : 0.0f;
  size_t base = (size_t)b * RNUM * N * N + rem;
  P[base + 0 * (size_t)N * N] = (_Float16)(mm * sigmoidf_(lg.x));
  P[base + 1 * (size_t)N * N] = (_Float16)(mm * sigmoidf_(lg.y));
  P[base + 2 * (size_t)N * N] = (_Float16)(mm * sigmoidf_(lg.z));
  P[base + 3 * (size_t)N * N] = (_Float16)(mm * sigmoidf_(lg.w));
}

// Work kernel (f16 path), two roles by blockIdx.x:
//  bid <  NCOLB : colsum role — Sum_c csum_c*(N-csum_c)  (factorized Sum(x))
//  bid >= NCOLB : main role — Sum |rab - a_c*b_c| via packed f16:
//    per 2 elements: v_pk_fma_f16 + v_and (packed abs) + v_dot2_f32_f16
//    = 1.5 VALU inst/elem, f32 accumulation via dot2.
//
// R10 journal (theory: real VALU occupancy is only ~33% — the derived
// VALUBusy uses gfx94x SIMD-16 formulas, ~2x over-report on gfx950 SIMD-32.
// Kernel is stall-bound, not issue-bound; R9's 4-blocks/CU cut TLP and lost):
//  * back to CT=32/CSPLIT=16 (R8 geometry, the better measured config).
//  * __launch_bounds__(256,8): 8 waves/SIMD target, VGPR cap 64. Estimated
//    live set: rab2 32 + acc 8 + cur tiles 8 + addr ~8 = ~56, should fit
//    with NO scratch (R8's VGPR=28 build likely spilled rab2 to scratch,
//    capping residency AND adding latency).
//  * consecutive-8 column mapping: thread owns a = a0+ta*8+{0..7},
//    b = b0+tb*8+{0..7}. Inner loop: 2x ds_read_b128 (was 4x b64) — 16-lane
//    x 16B contiguous, conflict-free; rab tile: 8x global dwordx4 (was 16x
//    dwordx2), row-contiguous 256B per 16-lane group.
//  * row-pair u32 staging kept (16 ds_write_b32/thread, 64-consecutive-dword
//    wave pattern = 2-way bank alias = free per m136).
__global__ __launch_bounds__(256, 8) void work_f16_kernel(const _Float16* __restrict__ P,
                                                          float* __restrict__ out) {
  __shared__ __align__(16) _Float16 tA[CT][LSTR];
  __shared__ __align__(16) _Float16 tB[CT][LSTR];
  __shared__ float wsum[4];

  const int tid = threadIdx.x;
  const int bid = blockIdx.x;

  if (bid < NCOLB) {
    // ---- colsum role ----
    const int s    = bid >> 1;
    const int half = bid & 1;
    const int c    = half * 256 + tid;
    const _Float16* col = P + (size_t)s * N * N + c;
    float sum = 0.0f;
#pragma unroll 16
    for (int a = 0; a < N; ++a) sum += (float)col[(size_t)a * N];
    float v = sum * ((float)N - sum);
    for (int off = 32; off > 0; off >>= 1) v += __shfl_down(v, off, 64);
    const int wid = tid >> 6;
    if ((tid & 63) == 0) wsum[wid] = v;
    __syncthreads();
    if (tid == 0)
      atomicAdd(out, (wsum[0] + wsum[1] + wsum[2] + wsum[3]) * SCALE);
    return;
  }

  // ---- main role ----
  const int m  = bid - NCOLB;
  const int bt = m & 3;
  const int at = (m >> 2) & 3;
  const int s  = (m >> 4) & 7;
  const int cz = m >> 7;                    // 0..CSPLIT-1
  const int a0 = at * TILE;
  const int b0 = bt * TILE;
  const int c0 = cz * CT;                   // exactly one CT-chunk per block

  const int ta = tid & 15;    // a cols: a0 + ta*8 + {0..7}
  const int tb = tid >> 4;    // b cols: b0 + tb*8 + {0..7}

  const _Float16* Ph = P + (size_t)s * N * N;

  // staging: thread transposes a ROW-PAIR (2 rows) x 16 c's, packing
  // {row0[c],row1[c]} u32 into LDS column pair (2p, 2p+1).
  // u = tid&127: pair-unit (u<64: A pairs, else B); h = tid>>7: c-half.
  {
    const int u   = tid & 127;
    const int h   = tid >> 7;
    const int isB = u >> 6;
    const int p   = u & 63;                 // pair index within tile
    const int r0  = (isB ? b0 : a0) + 2 * p;
    const int cc0 = c0 + h * 16;
    const _Float16* s0row = Ph + (size_t)r0 * N + cc0;
    const _Float16* s1row = s0row + N;
    _Float16* dst = isB ? &tB[h * 16][2 * p] : &tA[h * 16][2 * p];
    uint4 q0 = ((const uint4*)s0row)[0];
    uint4 q1 = ((const uint4*)s0row)[1];
    uint4 r0v = ((const uint4*)s1row)[0];
    uint4 r1v = ((const uint4*)s1row)[1];
    unsigned int w0[8] = {q0.x, q0.y, q0.z, q0.w, q1.x, q1.y, q1.z, q1.w};
    unsigned int w1[8] = {r0v.x, r0v.y, r0v.z, r0v.w, r1v.x, r1v.y, r1v.z, r1v.w};
#pragma unroll
    for (int k = 0; k < 8; ++k) {
      unsigned int lo = (w1[k] << 16) | (w0[k] & 0xFFFFu);       // c = 2k
      unsigned int hi = (w1[k] & 0xFFFF0000u) | (w0[k] >> 16);   // c = 2k+1
      *(unsigned int*)(dst + (size_t)(2 * k) * LSTR)     = lo;
      *(unsigned int*)(dst + (size_t)(2 * k + 1) * LSTR) = hi;
    }
  }

  // rab tile: 8 consecutive b's per a -> one dwordx4 per x.
  // rab2[x][yp] = {rab[x][2yp], rab[x][2yp+1]}
  half2_t rab2[8][4];
#pragma unroll
  for (int x = 0; x < 8; ++x) {
    int ga = a0 + ta * 8 + x;
    uint4 q = *(const uint4*)(Ph + (size_t)ga * N + b0 + tb * 8);
    rab2[x][0] = u2h(q.x); rab2[x][1] = u2h(q.y);
    rab2[x][2] = u2h(q.z); rab2[x][3] = u2h(q.w);
  }

  float acc[8];
#pragma unroll
  for (int x = 0; x < 8; ++x) acc[x] = 0.0f;

  const half2_t kOne = {(_Float16)1.0f, (_Float16)1.0f};

  __syncthreads();

#pragma unroll 4
  for (int c = 0; c < CT; ++c) {
    uint4 ua = *(const uint4*)&tA[c][ta * 8];   // 8 a-values (b128, conflict-free)
    uint4 ub = *(const uint4*)&tB[c][tb * 8];   // 8 b-values (broadcast within group)
    half2_t av[4] = {u2h(ua.x), u2h(ua.y), u2h(ua.z), u2h(ua.w)};
    half2_t bv[4] = {u2h(ub.x), u2h(ub.y), u2h(ub.z), u2h(ub.w)};
#pragma unroll
    for (int x = 0; x < 8; ++x) {
      _Float16 as = (x & 1) ? av[x >> 1].y : av[x >> 1].x;
      half2_t asp = {as, as};
      float a_ = acc[x];
#pragma unroll
      for (int yp = 0; yp < 4; ++yp) {
        half2_t t2 = rab2[x][yp] - asp * bv[yp];     // v_pk_fma_f16 (neg)
        half2_t p2 = u2h(h2u(t2) & 0x7FFF7FFFu);     // packed |t|
        a_ = fdot2_(p2, kOne, a_);                   // f32 accumulate
      }
      acc[x] = a_;
    }
  }

  float tsum = 0.0f;
#pragma unroll
  for (int x = 0; x < 8; ++x) tsum += acc[x];

  for (int off = 32; off > 0; off >>= 1) tsum += __shfl_down(tsum, off, 64);

  const int wid = tid >> 6;
  if ((tid & 63) == 0) wsum[wid] = tsum;
  __syncthreads();
  if (tid == 0)
    atomicAdd(out, (wsum[0] + wsum[1] + wsum[2] + wsum[3]) * SCALE);
}

// ---------------- f32 fallback (no workspace): R4 structure ----------------
#define FCT    64
#define FSTR   132
#define FCSPL  4

__global__ __launch_bounds__(256, 2) void work_f32_fallback(const float* __restrict__ logits,
                                                            const int* __restrict__ masks,
                                                            float* __restrict__ out) {
  __shared__ __align__(16) float tA[FCT][FSTR];
  __shared__ __align__(16) float tB[FCT][FSTR];
  __shared__ float wsum[4];

  const int tid = threadIdx.x;
  const int bid = blockIdx.x;

  if (bid < NCOLB) {
    const int s    = bid >> 1;
    const int half = bid & 1;
    const int c    = half * 256 + tid;
    const int bb   = s >> 2;
    const int r    = s & 3;
    const int* mrow = masks + bb * N;
    float mc = (mrow[c] > 0) ? 1.0f : 0.0f;
    float sum = 0.0f;
#pragma unroll 4
    for (int a = 0; a < N; ++a) {
      float ma = (mrow[a] > 0) ? 1.0f : 0.0f;
      size_t idx = ((size_t)(bb * N + a) * N + c) * RNUM + r;
      sum += sigmoidf_(logits[idx]) * ma * mc;
    }
    float v = sum * ((float)N - sum);
    for (int off = 32; off > 0; off >>= 1) v += __shfl_down(v, off, 64);
    const int wid = tid >> 6;
    if ((tid & 63) == 0) wsum[wid] = v;
    __syncthreads();
    if (tid == 0)
      atomicAdd(out, (wsum[0] + wsum[1] + wsum[2] + wsum[3]) * SCALE);
    return;
  }

  const int m  = bid - NCOLB;
  const int bt = m & 3;
  const int at = (m >> 2) & 3;
  const int s  = (m >> 4) & 7;
  const int cz = m >> 7;
  const int a0 = at * TILE;
  const int b0 = bt * TILE;
  const int bb = s >> 2;
  const int r  = s & 3;
  const int cbeg = cz * (N / FCSPL);
  const int cend = cbeg + (N / FCSPL);

  const int ta = tid & 15;
  const int tb = tid >> 4;
  const int* mrow = masks + bb * N;

  float rab[8][8];
#pragma unroll
  for (int x = 0; x < 8; ++x) {
    int ra = a0 + ((x >> 2) << 6) + ta * 4 + (x & 3);
    float ma = (mrow[ra] > 0) ? 1.0f : 0.0f;
#pragma unroll
    for (int y = 0; y < 8; ++y) {
      int cb = b0 + ((y >> 2) << 6) + tb * 4 + (y & 3);
      float mb = (mrow[cb] > 0) ? 1.0f : 0.0f;
      size_t idx = ((size_t)(bb * N + ra) * N + cb) * RNUM + r;
      rab[x][y] = sigmoidf_(logits[idx]) * ma * mb;
    }
  }

  float acc[8][2];
#pragma unroll
  for (int x = 0; x < 8; ++x) { acc[x][0] = 0.0f; acc[x][1] = 0.0f; }

  for (int c0 = cbeg; c0 < cend; c0 += FCT) {
    __syncthreads();
#pragma unroll
    for (int it = 0; it < 32; ++it) {
      int e = it * 256 + tid;
      int c = e & 63;
      int i = e >> 6;
      int pc = ((((i >> 2) ^ ((c >> 2) & 31)) & 31) << 2) | (i & 3);
      float mc = (mrow[c0 + c] > 0) ? 1.0f : 0.0f;
      {
        float mi = (mrow[a0 + i] > 0) ? 1.0f : 0.0f;
        size_t idx = ((size_t)(bb * N + a0 + i) * N + (c0 + c)) * RNUM + r;
        tA[c][pc] = sigmoidf_(logits[idx]) * mi * mc;
      }
      {
        float mi = (mrow[b0 + i] > 0) ? 1.0f : 0.0f;
        size_t idx = ((size_t)(bb * N + b0 + i) * N + (c0 + c)) * RNUM + r;
        tB[c][pc] = sigmoidf_(logits[idx]) * mi * mc;
      }
    }
    __syncthreads();

#pragma unroll 2
    for (int cg = 0; cg < FCT / 4; ++cg) {
      const float* pa = &tA[cg * 4][((ta ^ cg) & 31) << 2];
      const float* pb = &tB[cg * 4][((tb ^ cg) & 31) << 2];
#pragma unroll
      for (int dc = 0; dc < 4; ++dc) {
        float4 a0v = *(const float4*)(pa + dc * FSTR);
        float4 a1v = *(const float4*)(pa + dc * FSTR + 64);
        float4 b0v = *(const float4*)(pb + dc * FSTR);
        float4 b1v = *(const float4*)(pb + dc * FSTR + 64);
        float avv[8] = {a0v.x, a0v.y, a0v.z, a0v.w, a1v.x, a1v.y, a1v.z, a1v.w};
        float bvv[8] = {b0v.x, b0v.y, b0v.z, b0v.w, b1v.x, b1v.y, b1v.z, b1v.w};
#pragma unroll
        for (int x = 0; x < 8; ++x) {
#pragma unroll
          for (int y = 0; y < 4; ++y)
            acc[x][0] += fabsf(fmaf(-avv[x], bvv[y], rab[x][y]));
#pragma unroll
          for (int y = 4; y < 8; ++y)
            acc[x][1] += fabsf(fmaf(-avv[x], bvv[y], rab[x][y]));
        }
      }
    }
  }

  float tsum = 0.0f;
#pragma unroll
  for (int x = 0; x < 8; ++x) tsum += acc[x][0] + acc[x][1];
  for (int off = 32; off > 0; off >>= 1) tsum += __shfl_down(tsum, off, 64);
  const int wid = tid >> 6;
  if ((tid & 63) == 0) wsum[wid] = tsum;
  __syncthreads();
  if (tid == 0)
    atomicAdd(out, (wsum[0] + wsum[1] + wsum[2] + wsum[3]) * SCALE);
}

extern "C" void kernel_launch(void* const* d_in, const int* in_sizes, int n_in,
                              void* d_out, int out_size, void* d_ws, size_t ws_size,
                              hipStream_t stream) {
  const float* logits = (const float*)d_in[0];
  const int*   masks  = (const int*)d_in[1];
  float*       out    = (float*)d_out;

  const size_t P_BYTES = (size_t)NSLICE * N * N * sizeof(_Float16);  // 4 MB

  if (ws_size >= P_BYTES) {
    _Float16* P = (_Float16*)d_ws;
    prep_f16_kernel<<<(BNUM * N * N) / 256, 256, 0, stream>>>(logits, masks, P, out);
    const int nblocks = NCOLB + 4 * 4 * NSLICE * CSPLIT;  // 16 + 2048
    work_f16_kernel<<<nblocks, 256, 0, stream>>>(P, out);
  } else {
    zero_out_kernel<<<1, 1, 0, stream>>>(out);
    const int nblocks = NCOLB + 4 * 4 * NSLICE * FCSPL;   // 16 + 512
    work_f32_fallback<<<nblocks, 256, 0, stream>>>(logits, masks, out);
  }
}